// Round 1
// baseline (5294.975 us; speedup 1.0000x reference)
//
#include <hip/hip_runtime.h>
#include <cmath>

#define DEV_INLINE __device__ __forceinline__

constexpr int B_ = 8, T_ = 16, INPUT_ = 64, OUTPUT_ = 128;
constexpr int N_ = 256, H_ = 256, KQ_ = 256, S_ = 256, G_ = 1024; // G_ = 4*H
constexpr int NIN_ = 32;
constexpr float SCALE_ = 0.0625f; // 1/sqrt(256)

DEV_INLINE float sigmoid_(float x) { return 1.0f / (1.0f + expf(-x)); }

// ---------------------------------------------------------------------------
// Generic per-neuron matmul: out[b][n][g] = sum_h in[b][n][h] * W[n][h][g] + bias[n][g]
// grid = (n_streams, N). block = 256 (one lane per output column g).
// Inputs staged to LDS transposed [h][b] so the inner loop reads 2x float4
// broadcasts; weight reads are fully coalesced dword streams.
// ---------------------------------------------------------------------------
__global__ __launch_bounds__(256, 4)
void pn_mm_kernel(const float* __restrict__ in,
                  const float* __restrict__ W0, const float* __restrict__ bias0,
                  float* __restrict__ out0,
                  const float* __restrict__ W1, const float* __restrict__ bias1,
                  float* __restrict__ out1)
{
    __shared__ float sh[H_ * B_];
    const int n = blockIdx.y;
    const int s = blockIdx.x;
    const int tid = threadIdx.x;
    for (int idx = tid; idx < H_ * B_; idx += 256) {
        int b = idx & 7, hh = idx >> 3;
        sh[idx] = in[(size_t)(b * N_ + n) * H_ + hh];
    }
    __syncthreads();
    const float* W = s ? W1 : W0;
    const float* bias = s ? bias1 : bias0;
    float* out = s ? out1 : out0;

    const float* wp = W + (size_t)n * H_ * 256 + tid;
    float acc[8] = {0.f, 0.f, 0.f, 0.f, 0.f, 0.f, 0.f, 0.f};
#pragma unroll 8
    for (int hh = 0; hh < H_; ++hh) {
        float w = wp[(size_t)hh * 256];
        float4 i0 = *(const float4*)&sh[hh * 8];
        float4 i1 = *(const float4*)&sh[hh * 8 + 4];
        acc[0] += w * i0.x; acc[1] += w * i0.y; acc[2] += w * i0.z; acc[3] += w * i0.w;
        acc[4] += w * i1.x; acc[5] += w * i1.y; acc[6] += w * i1.z; acc[7] += w * i1.w;
    }
    float bv = bias[n * 256 + tid];
#pragma unroll
    for (int b = 0; b < 8; ++b)
        out[(size_t)(b * N_ + n) * 256 + tid] = acc[b] + bv;
}

// ---------------------------------------------------------------------------
// Gates: gates[b][n][g] = sum_h lin[b][n][h]*Wih[n][h][g] + hbuf[..]*Whh[..] + biases
// grid = (4, N): 4 chunks of 256 gate columns. Two fused weight streams.
// ---------------------------------------------------------------------------
__global__ __launch_bounds__(256, 4)
void gates_kernel(const float* __restrict__ lin, const float* __restrict__ hbuf,
                  const float* __restrict__ wih, const float* __restrict__ bih,
                  const float* __restrict__ whh, const float* __restrict__ bhh,
                  float* __restrict__ gates)
{
    __shared__ float shi[H_ * B_];
    __shared__ float shh[H_ * B_];
    const int n = blockIdx.y;
    const int g = blockIdx.x * 256 + threadIdx.x;
    const int tid = threadIdx.x;
    for (int idx = tid; idx < H_ * B_; idx += 256) {
        int b = idx & 7, hh = idx >> 3;
        int src = (b * N_ + n) * H_ + hh;
        shi[idx] = lin[src];
        shh[idx] = hbuf[src];
    }
    __syncthreads();
    const float* wi = wih + (size_t)n * H_ * G_ + g;
    const float* wh = whh + (size_t)n * H_ * G_ + g;
    float acc[8] = {0.f, 0.f, 0.f, 0.f, 0.f, 0.f, 0.f, 0.f};
#pragma unroll 8
    for (int hh = 0; hh < H_; ++hh) {
        float a = wi[(size_t)hh * G_];
        float c = wh[(size_t)hh * G_];
        float4 i0 = *(const float4*)&shi[hh * 8];
        float4 i1 = *(const float4*)&shi[hh * 8 + 4];
        float4 h0 = *(const float4*)&shh[hh * 8];
        float4 h1 = *(const float4*)&shh[hh * 8 + 4];
        acc[0] += a * i0.x + c * h0.x;
        acc[1] += a * i0.y + c * h0.y;
        acc[2] += a * i0.z + c * h0.z;
        acc[3] += a * i0.w + c * h0.w;
        acc[4] += a * i1.x + c * h1.x;
        acc[5] += a * i1.y + c * h1.y;
        acc[6] += a * i1.z + c * h1.z;
        acc[7] += a * i1.w + c * h1.w;
    }
    float bv = bih[n * G_ + g] + bhh[n * G_ + g];
#pragma unroll
    for (int b = 0; b < 8; ++b)
        gates[(size_t)(b * N_ + n) * G_ + g] = acc[b] + bv;
}

// ---------------------------------------------------------------------------
// rec: lstm_in[b][n][h] = relu( n<32 ? x_t[b] @ w_rec_input[n] + b_rec_input[n]
//                                     : ctx[b][n] @ w_rec_other[n-32] + b_rec_other[n-32] )
// grid = N. Branch is block-uniform (no divergence).
// ---------------------------------------------------------------------------
__global__ __launch_bounds__(256, 4)
void rec_kernel(const float* __restrict__ x, int t,
                const float* __restrict__ w_ri, const float* __restrict__ b_ri,
                const float* __restrict__ ctx,
                const float* __restrict__ w_ro, const float* __restrict__ b_ro,
                float* __restrict__ lin)
{
    __shared__ float sh[H_ * B_];
    const int n = blockIdx.x;
    const int tid = threadIdx.x;
    float acc[8] = {0.f, 0.f, 0.f, 0.f, 0.f, 0.f, 0.f, 0.f};
    float bv;
    if (n < NIN_) {
        for (int idx = tid; idx < INPUT_ * B_; idx += 256) {
            int b = idx & 7, hh = idx >> 3;
            sh[idx] = x[((size_t)b * T_ + t) * INPUT_ + hh];
        }
        __syncthreads();
        const float* wp = w_ri + (size_t)n * INPUT_ * H_ + tid;
#pragma unroll 8
        for (int hh = 0; hh < INPUT_; ++hh) {
            float w = wp[(size_t)hh * H_];
            float4 i0 = *(const float4*)&sh[hh * 8];
            float4 i1 = *(const float4*)&sh[hh * 8 + 4];
            acc[0] += w * i0.x; acc[1] += w * i0.y; acc[2] += w * i0.z; acc[3] += w * i0.w;
            acc[4] += w * i1.x; acc[5] += w * i1.y; acc[6] += w * i1.z; acc[7] += w * i1.w;
        }
        bv = b_ri[n * H_ + tid];
    } else {
        for (int idx = tid; idx < S_ * B_; idx += 256) {
            int b = idx & 7, hh = idx >> 3;
            sh[idx] = ctx[(size_t)(b * N_ + n) * S_ + hh];
        }
        __syncthreads();
        const float* wp = w_ro + (size_t)(n - NIN_) * S_ * H_ + tid;
#pragma unroll 8
        for (int hh = 0; hh < S_; ++hh) {
            float w = wp[(size_t)hh * H_];
            float4 i0 = *(const float4*)&sh[hh * 8];
            float4 i1 = *(const float4*)&sh[hh * 8 + 4];
            acc[0] += w * i0.x; acc[1] += w * i0.y; acc[2] += w * i0.z; acc[3] += w * i0.w;
            acc[4] += w * i1.x; acc[5] += w * i1.y; acc[6] += w * i1.z; acc[7] += w * i1.w;
        }
        bv = b_ro[(n - NIN_) * H_ + tid];
    }
#pragma unroll
    for (int b = 0; b < 8; ++b)
        lin[(size_t)(b * N_ + n) * H_ + tid] = fmaxf(acc[b] + bv, 0.f);
}

// ---------------------------------------------------------------------------
// scores[b][n][m] = SCALE * sum_h Q[b][n][h] * K[b][m][h]   (A @ B^T, 64x64 tiles)
// grid = (16, B), block = 256, 4x4 per thread, BK=16.
// ---------------------------------------------------------------------------
__global__ void scores_kernel(const float* __restrict__ Q, const float* __restrict__ Kb,
                              float* __restrict__ sc)
{
    __shared__ float As[16][64];
    __shared__ float Bs[16][64];
    const int b = blockIdx.y;
    const int tile = blockIdx.x;
    const int row0 = (tile >> 2) * 64;
    const int col0 = (tile & 3) * 64;
    const int tid = threadIdx.x;
    const int tx = tid & 15, ty = tid >> 4;
    const int lr = tid >> 2;            // 0..63 staging row
    const int kq = (tid & 3) * 4;       // k quad
    const float* Qb = Q + (size_t)b * N_ * KQ_;
    const float* Kbb = Kb + (size_t)b * N_ * KQ_;
    float acc[4][4] = {};
    for (int kt = 0; kt < KQ_; kt += 16) {
        float4 av = *(const float4*)&Qb[(size_t)(row0 + lr) * KQ_ + kt + kq];
        float4 bv = *(const float4*)&Kbb[(size_t)(col0 + lr) * KQ_ + kt + kq];
        __syncthreads();
        As[kq + 0][lr] = av.x; As[kq + 1][lr] = av.y; As[kq + 2][lr] = av.z; As[kq + 3][lr] = av.w;
        Bs[kq + 0][lr] = bv.x; Bs[kq + 1][lr] = bv.y; Bs[kq + 2][lr] = bv.z; Bs[kq + 3][lr] = bv.w;
        __syncthreads();
#pragma unroll
        for (int k = 0; k < 16; ++k) {
            float4 a = *(const float4*)&As[k][ty * 4];
            float4 c = *(const float4*)&Bs[k][tx * 4];
            acc[0][0] += a.x * c.x; acc[0][1] += a.x * c.y; acc[0][2] += a.x * c.z; acc[0][3] += a.x * c.w;
            acc[1][0] += a.y * c.x; acc[1][1] += a.y * c.y; acc[1][2] += a.y * c.z; acc[1][3] += a.y * c.w;
            acc[2][0] += a.z * c.x; acc[2][1] += a.z * c.y; acc[2][2] += a.z * c.z; acc[2][3] += a.z * c.w;
            acc[3][0] += a.w * c.x; acc[3][1] += a.w * c.y; acc[3][2] += a.w * c.z; acc[3][3] += a.w * c.w;
        }
    }
#pragma unroll
    for (int i = 0; i < 4; ++i) {
        float4 r = make_float4(acc[i][0] * SCALE_, acc[i][1] * SCALE_,
                               acc[i][2] * SCALE_, acc[i][3] * SCALE_);
        *(float4*)&sc[((size_t)b * N_ + row0 + ty * 4 + i) * N_ + col0 + tx * 4] = r;
    }
}

// ---------------------------------------------------------------------------
// in-place row softmax over m: sc[b][n][:]
// ---------------------------------------------------------------------------
__global__ void softmax_kernel(float* __restrict__ sc)
{
    const int n = blockIdx.x, b = blockIdx.y;
    const int tid = threadIdx.x;
    __shared__ float red[256];
    float* row = sc + ((size_t)b * N_ + n) * N_;
    float v = row[tid];
    red[tid] = v;
    __syncthreads();
    for (int s = 128; s > 0; s >>= 1) {
        if (tid < s) red[tid] = fmaxf(red[tid], red[tid + s]);
        __syncthreads();
    }
    float m = red[0];
    __syncthreads();
    float e = expf(v - m);
    red[tid] = e;
    __syncthreads();
    for (int s = 128; s > 0; s >>= 1) {
        if (tid < s) red[tid] += red[tid + s];
        __syncthreads();
    }
    row[tid] = e / red[0];
}

// ---------------------------------------------------------------------------
// ctx[b][n][s] = sum_m W[b][n][m] * prev[b][m][s]   (A @ B, 64x64 tiles)
// ---------------------------------------------------------------------------
__global__ void ctx_kernel(const float* __restrict__ W, const float* __restrict__ prev,
                           float* __restrict__ ctx)
{
    __shared__ float As[16][64];
    __shared__ float Bs[16][64];
    const int b = blockIdx.y;
    const int tile = blockIdx.x;
    const int row0 = (tile >> 2) * 64;
    const int col0 = (tile & 3) * 64;
    const int tid = threadIdx.x;
    const int tx = tid & 15, ty = tid >> 4;
    const int lr = tid >> 2;
    const int kq = (tid & 3) * 4;
    const int br = tid >> 4;            // 0..15 B-staging row
    const int bc = (tid & 15) * 4;      // B-staging col quad
    const float* Wb = W + (size_t)b * N_ * N_;
    const float* pb = prev + (size_t)b * N_ * S_;
    float acc[4][4] = {};
    for (int kt = 0; kt < N_; kt += 16) {
        float4 av = *(const float4*)&Wb[(size_t)(row0 + lr) * N_ + kt + kq];
        float4 bv = *(const float4*)&pb[(size_t)(kt + br) * S_ + col0 + bc];
        __syncthreads();
        As[kq + 0][lr] = av.x; As[kq + 1][lr] = av.y; As[kq + 2][lr] = av.z; As[kq + 3][lr] = av.w;
        *(float4*)&Bs[br][bc] = bv;
        __syncthreads();
#pragma unroll
        for (int k = 0; k < 16; ++k) {
            float4 a = *(const float4*)&As[k][ty * 4];
            float4 c = *(const float4*)&Bs[k][tx * 4];
            acc[0][0] += a.x * c.x; acc[0][1] += a.x * c.y; acc[0][2] += a.x * c.z; acc[0][3] += a.x * c.w;
            acc[1][0] += a.y * c.x; acc[1][1] += a.y * c.y; acc[1][2] += a.y * c.z; acc[1][3] += a.y * c.w;
            acc[2][0] += a.z * c.x; acc[2][1] += a.z * c.y; acc[2][2] += a.z * c.z; acc[2][3] += a.z * c.w;
            acc[3][0] += a.w * c.x; acc[3][1] += a.w * c.y; acc[3][2] += a.w * c.z; acc[3][3] += a.w * c.w;
        }
    }
#pragma unroll
    for (int i = 0; i < 4; ++i) {
        float4 r = make_float4(acc[i][0], acc[i][1], acc[i][2], acc[i][3]);
        *(float4*)&ctx[((size_t)b * N_ + row0 + ty * 4 + i) * S_ + col0 + tx * 4] = r;
    }
}

// ---------------------------------------------------------------------------
// LSTM cell: elementwise over B*N*H
// ---------------------------------------------------------------------------
__global__ void cell_kernel(const float* __restrict__ gates, float* __restrict__ c,
                            float* __restrict__ h)
{
    const int tid = blockIdx.x * 256 + threadIdx.x;
    const int bn = tid >> 8;
    const int hx = tid & 255;
    const size_t gb = (size_t)bn * G_;
    float ig = gates[gb + hx];
    float fg = gates[gb + H_ + hx];
    float gg = gates[gb + 2 * H_ + hx];
    float og = gates[gb + 3 * H_ + hx];
    float cv = c[tid];
    float cn = sigmoid_(fg) * cv + sigmoid_(ig) * tanhf(gg);
    float hn = sigmoid_(og) * tanhf(cn);
    c[tid] = cn;
    h[tid] = hn;
}

// ---------------------------------------------------------------------------
// proj: out[b][t][o] = sum_j prev[b][224..255][:].flat[j] * w_proj[o][j] + b_proj[o]
// grid = OUTPUT (one block per o)
// ---------------------------------------------------------------------------
__global__ void proj_kernel(const float* __restrict__ prev, const float* __restrict__ wp,
                            const float* __restrict__ bp, float* __restrict__ out, int t)
{
    const int o = blockIdx.x;
    const int tid = threadIdx.x;
    float acc[8] = {0.f, 0.f, 0.f, 0.f, 0.f, 0.f, 0.f, 0.f};
    const float* wr = wp + (size_t)o * (32 * S_);
    for (int j = tid; j < 32 * S_; j += 256) {
        float w = wr[j];
#pragma unroll
        for (int b = 0; b < 8; ++b)
            acc[b] += w * prev[(size_t)b * N_ * S_ + 224 * S_ + j];
    }
    __shared__ float red[256];
#pragma unroll
    for (int b = 0; b < 8; ++b) {
        red[tid] = acc[b];
        __syncthreads();
        for (int s = 128; s > 0; s >>= 1) {
            if (tid < s) red[tid] += red[tid + s];
            __syncthreads();
        }
        if (tid == 0) out[((size_t)b * T_ + t) * OUTPUT_ + o] = red[0] + bp[o];
        __syncthreads();
    }
}

// ---------------------------------------------------------------------------
extern "C" void kernel_launch(void* const* d_in, const int* in_sizes, int n_in,
                              void* d_out, int out_size, void* d_ws, size_t ws_size,
                              hipStream_t stream)
{
    (void)in_sizes; (void)n_in; (void)out_size; (void)ws_size;
    const float* x    = (const float*)d_in[0];
    const float* w_ri = (const float*)d_in[1];
    const float* b_ri = (const float*)d_in[2];
    const float* w_ro = (const float*)d_in[3];
    const float* b_ro = (const float*)d_in[4];
    const float* w_ih = (const float*)d_in[5];
    const float* b_ih = (const float*)d_in[6];
    const float* w_hh = (const float*)d_in[7];
    const float* b_hh = (const float*)d_in[8];
    const float* w_q  = (const float*)d_in[9];
    const float* b_q  = (const float*)d_in[10];
    const float* w_k  = (const float*)d_in[11];
    const float* b_k  = (const float*)d_in[12];
    const float* w_s  = (const float*)d_in[13];
    const float* b_s  = (const float*)d_in[14];
    const float* w_p  = (const float*)d_in[15];
    const float* b_p  = (const float*)d_in[16];
    float* out = (float*)d_out;

    float* ws = (float*)d_ws;
    const size_t SZ = (size_t)B_ * N_ * H_; // 524288
    float* hbuf  = ws;
    float* cbuf  = hbuf + SZ;
    float* prev  = cbuf + SZ;
    float* Q     = prev + SZ;
    float* Kb    = Q + SZ;
    float* sc    = Kb + SZ;   // scores, softmaxed in place
    float* ctx   = sc + SZ;
    float* lin   = ctx + SZ;
    float* gates = lin + SZ;  // 4*SZ

    // zero h, c, prev (d_ws is poisoned before every timed call)
    hipMemsetAsync(d_ws, 0, 3 * SZ * sizeof(float), stream);

    for (int t = 0; t < T_; ++t) {
        pn_mm_kernel<<<dim3(2, N_), 256, 0, stream>>>(hbuf, w_q, b_q, Q, w_k, b_k, Kb);
        scores_kernel<<<dim3(16, B_), 256, 0, stream>>>(Q, Kb, sc);
        softmax_kernel<<<dim3(N_, B_), 256, 0, stream>>>(sc);
        ctx_kernel<<<dim3(16, B_), 256, 0, stream>>>(sc, prev, ctx);
        rec_kernel<<<dim3(N_), 256, 0, stream>>>(x, t, w_ri, b_ri, ctx, w_ro, b_ro, lin);
        gates_kernel<<<dim3(4, N_), 256, 0, stream>>>(lin, hbuf, w_ih, b_ih, w_hh, b_hh, gates);
        cell_kernel<<<dim3((B_ * N_ * H_) / 256), 256, 0, stream>>>(gates, cbuf, hbuf);
        pn_mm_kernel<<<dim3(1, N_), 256, 0, stream>>>(hbuf, w_s, b_s, prev, w_s, b_s, prev);
        proj_kernel<<<dim3(OUTPUT_), 256, 0, stream>>>(prev, w_p, b_p, out, t);
    }
}

// Round 2
// 4471.649 us; speedup vs baseline: 1.1841x; 1.1841x over previous
//
#include <hip/hip_runtime.h>
#include <cmath>

#define DEV_INLINE __device__ __forceinline__

constexpr int B_ = 8, T_ = 16, INPUT_ = 64, OUTPUT_ = 128;
constexpr int N_ = 256, H_ = 256, KQ_ = 256, S_ = 256, G_ = 1024; // G_ = 4*H
constexpr int NIN_ = 32;
constexpr float SCALE_ = 0.0625f; // 1/sqrt(256)

DEV_INLINE float sigmoid_(float x) { return 1.0f / (1.0f + expf(-x)); }
DEV_INLINE void fma4(float4& a, const float4& w, float s) {
    a.x += w.x * s; a.y += w.y * s; a.z += w.z * s; a.w += w.w * s;
}

// ---------------------------------------------------------------------------
// pnmm64: P[split][b][n][c] = sum_{h in split} in[b][n][h] * W[ny][h][c]
// One wave per block; each lane owns 4 consecutive output cols (dwordx4
// weight loads). KU=8 register ping-pong keeps 8 KB/wave in flight.
// grid = (KS=4, nCount, nz); blockIdx.z selects (W0,P0)/(W1,P1) for QK fusion.
// ---------------------------------------------------------------------------
__global__ __launch_bounds__(64)
void pnmm64_kernel(const float* __restrict__ in,
                   const float* __restrict__ W0, float* __restrict__ P0,
                   const float* __restrict__ W1, float* __restrict__ P1,
                   int n0)
{
    constexpr int KS = 4, HS = 256 / KS; // 64 hh per split
    const int ny = blockIdx.y;
    const int n = n0 + ny;
    const int split = blockIdx.x;
    const int lane = threadIdx.x;
    const int c0 = lane * 4;
    const int h0 = split * HS;
    const float* W = blockIdx.z ? W1 : W0;
    float* P = blockIdx.z ? P1 : P0;

    __shared__ float sh[HS * 8]; // [hh][b]
    for (int i = lane; i < HS * 8; i += 64) {
        int hh = i & (HS - 1), b = i >> 6;
        sh[hh * 8 + b] = in[(size_t)(b * N_ + n) * 256 + h0 + hh];
    }
    __syncthreads();

    const float* wp = W + ((size_t)ny * 256 + h0) * 256 + c0;
    float4 acc[8] = {};
    float4 bufA[8], bufB[8];
#pragma unroll
    for (int u = 0; u < 8; ++u) bufA[u] = *(const float4*)(wp + (size_t)u * 256);
#pragma unroll 1
    for (int hb = 0; hb < HS; hb += 8) {
        if (hb + 8 < HS) {
#pragma unroll
            for (int u = 0; u < 8; ++u)
                bufB[u] = *(const float4*)(wp + (size_t)(hb + 8 + u) * 256);
        }
#pragma unroll
        for (int u = 0; u < 8; ++u) {
            float4 w = bufA[u];
            const float* ip = &sh[(hb + u) * 8];
            float4 i0 = *(const float4*)ip;
            float4 i1 = *(const float4*)(ip + 4);
            fma4(acc[0], w, i0.x); fma4(acc[1], w, i0.y);
            fma4(acc[2], w, i0.z); fma4(acc[3], w, i0.w);
            fma4(acc[4], w, i1.x); fma4(acc[5], w, i1.y);
            fma4(acc[6], w, i1.z); fma4(acc[7], w, i1.w);
        }
#pragma unroll
        for (int u = 0; u < 8; ++u) bufA[u] = bufB[u];
    }
#pragma unroll
    for (int b = 0; b < 8; ++b)
        *(float4*)&P[(((size_t)split * 8 + b) * N_ + n) * 256 + c0] = acc[b];
}

// ---------------------------------------------------------------------------
// gates_mm: P[split][b][n][g] = sum_{h in split} lin*Wih + h*Whh
// grid = (2, 256), block 256. Each thread 4 cols of 1024; KU=4 ping-pong on
// both weight streams (8 KB/wave in flight). Biases folded into cell_kernel.
// ---------------------------------------------------------------------------
__global__ __launch_bounds__(256)
void gates_mm_kernel(const float* __restrict__ lin, const float* __restrict__ hbuf,
                     const float* __restrict__ wih, const float* __restrict__ whh,
                     float* __restrict__ P)
{
    constexpr int KS = 2, HS = 256 / KS; // 128 hh per split
    const int n = blockIdx.y;
    const int split = blockIdx.x;
    const int tid = threadIdx.x;
    const int c0 = tid * 4;
    const int h0 = split * HS;

    __shared__ float shi[HS * 8];
    __shared__ float shh[HS * 8];
    for (int i = tid; i < HS * 8; i += 256) {
        int hh = i & (HS - 1), b = i >> 7;
        int src = (b * N_ + n) * H_ + h0 + hh;
        shi[hh * 8 + b] = lin[src];
        shh[hh * 8 + b] = hbuf[src];
    }
    __syncthreads();

    const float* wi = wih + ((size_t)n * H_ + h0) * G_ + c0;
    const float* wh = whh + ((size_t)n * H_ + h0) * G_ + c0;
    float4 acc[8] = {};
    float4 biA[4], bhA[4], biB[4], bhB[4];
#pragma unroll
    for (int u = 0; u < 4; ++u) {
        biA[u] = *(const float4*)(wi + (size_t)u * G_);
        bhA[u] = *(const float4*)(wh + (size_t)u * G_);
    }
#pragma unroll 1
    for (int hb = 0; hb < HS; hb += 4) {
        if (hb + 4 < HS) {
#pragma unroll
            for (int u = 0; u < 4; ++u) {
                biB[u] = *(const float4*)(wi + (size_t)(hb + 4 + u) * G_);
                bhB[u] = *(const float4*)(wh + (size_t)(hb + 4 + u) * G_);
            }
        }
#pragma unroll
        for (int u = 0; u < 4; ++u) {
            float4 a = biA[u];
            float4 h = bhA[u];
            const float* ip = &shi[(hb + u) * 8];
            const float* hp = &shh[(hb + u) * 8];
            float4 i0 = *(const float4*)ip;
            float4 i1 = *(const float4*)(ip + 4);
            float4 h0v = *(const float4*)hp;
            float4 h1v = *(const float4*)(hp + 4);
            fma4(acc[0], a, i0.x); fma4(acc[0], h, h0v.x);
            fma4(acc[1], a, i0.y); fma4(acc[1], h, h0v.y);
            fma4(acc[2], a, i0.z); fma4(acc[2], h, h0v.z);
            fma4(acc[3], a, i0.w); fma4(acc[3], h, h0v.w);
            fma4(acc[4], a, i1.x); fma4(acc[4], h, h1v.x);
            fma4(acc[5], a, i1.y); fma4(acc[5], h, h1v.y);
            fma4(acc[6], a, i1.z); fma4(acc[6], h, h1v.z);
            fma4(acc[7], a, i1.w); fma4(acc[7], h, h1v.w);
        }
#pragma unroll
        for (int u = 0; u < 4; ++u) { biA[u] = biB[u]; bhA[u] = bhB[u]; }
    }
#pragma unroll
    for (int b = 0; b < 8; ++b)
        *(float4*)&P[(((size_t)split * 8 + b) * N_ + n) * G_ + c0] = acc[b];
}

// ---------------------------------------------------------------------------
// rec_in: lin[b][n][h] = relu(x_t @ w_rec_input + b), n < 32 only (2 MB wts)
// ---------------------------------------------------------------------------
__global__ __launch_bounds__(256)
void rec_in_kernel(const float* __restrict__ x, int t,
                   const float* __restrict__ w_ri, const float* __restrict__ b_ri,
                   float* __restrict__ lin)
{
    __shared__ float sh[INPUT_ * 8];
    const int n = blockIdx.x;
    const int tid = threadIdx.x;
    for (int i = tid; i < INPUT_ * 8; i += 256) {
        int hh = i & 63, b = i >> 6;
        sh[hh * 8 + b] = x[((size_t)b * T_ + t) * INPUT_ + hh];
    }
    __syncthreads();
    const float* wp = w_ri + (size_t)n * INPUT_ * H_ + tid;
    float acc[8] = {};
#pragma unroll 8
    for (int hh = 0; hh < INPUT_; ++hh) {
        float w = wp[(size_t)hh * H_];
        float4 i0 = *(const float4*)&sh[hh * 8];
        float4 i1 = *(const float4*)&sh[hh * 8 + 4];
        acc[0] += w * i0.x; acc[1] += w * i0.y; acc[2] += w * i0.z; acc[3] += w * i0.w;
        acc[4] += w * i1.x; acc[5] += w * i1.y; acc[6] += w * i1.z; acc[7] += w * i1.w;
    }
    float bv = b_ri[n * H_ + tid];
#pragma unroll
    for (int b = 0; b < 8; ++b)
        lin[(size_t)(b * N_ + n) * H_ + tid] = fmaxf(acc[b] + bv, 0.f);
}

// ---------------------------------------------------------------------------
// reduce4: out[b][n0+nn][h] = (relu?) sum_{s<4} P[s][b][n0+nn][h] + bias[nn][h]
// grid = 8*nCount*64/256 blocks of 256 (float4 per thread)
// ---------------------------------------------------------------------------
__global__ __launch_bounds__(256)
void reduce4_kernel(const float* __restrict__ P, const float* __restrict__ bias,
                    float* __restrict__ out, int n0, int nCount, int relu)
{
    const int idx = blockIdx.x * 256 + threadIdx.x;
    const int h4 = idx & 63;
    const int rest = idx >> 6;
    const int nn = rest % nCount;
    const int b = rest / nCount;
    const int n = n0 + nn;
    float4 s = *(const float4*)&bias[nn * 256 + h4 * 4];
#pragma unroll
    for (int sp = 0; sp < 4; ++sp) {
        float4 p = *(const float4*)&P[(((size_t)sp * 8 + b) * N_ + n) * 256 + h4 * 4];
        s.x += p.x; s.y += p.y; s.z += p.z; s.w += p.w;
    }
    if (relu) {
        s.x = fmaxf(s.x, 0.f); s.y = fmaxf(s.y, 0.f);
        s.z = fmaxf(s.z, 0.f); s.w = fmaxf(s.w, 0.f);
    }
    *(float4*)&out[((size_t)b * N_ + n) * 256 + h4 * 4] = s;
}

// reduceQK: same but for the two 4-split partial stacks of Q and K
__global__ __launch_bounds__(256)
void reduceQK_kernel(const float* __restrict__ Pq, const float* __restrict__ Pk,
                     const float* __restrict__ bq, const float* __restrict__ bk,
                     float* __restrict__ Q, float* __restrict__ K)
{
    const int z = blockIdx.y;
    const float* P = z ? Pk : Pq;
    const float* bias = z ? bk : bq;
    float* out = z ? K : Q;
    const int idx = blockIdx.x * 256 + threadIdx.x;
    const int h4 = idx & 63;
    const int rest = idx >> 6;
    const int n = rest & 255;
    const int b = rest >> 8;
    float4 s = *(const float4*)&bias[n * 256 + h4 * 4];
#pragma unroll
    for (int sp = 0; sp < 4; ++sp) {
        float4 p = *(const float4*)&P[(((size_t)sp * 8 + b) * N_ + n) * 256 + h4 * 4];
        s.x += p.x; s.y += p.y; s.z += p.z; s.w += p.w;
    }
    *(float4*)&out[((size_t)b * N_ + n) * 256 + h4 * 4] = s;
}

// ---------------------------------------------------------------------------
// scores[b][n][m] = SCALE * sum_h Q[b][n][h] * K[b][m][h]   (A @ B^T, 64x64)
// ---------------------------------------------------------------------------
__global__ void scores_kernel(const float* __restrict__ Q, const float* __restrict__ Kb,
                              float* __restrict__ sc)
{
    __shared__ float As[16][64];
    __shared__ float Bs[16][64];
    const int b = blockIdx.y;
    const int tile = blockIdx.x;
    const int row0 = (tile >> 2) * 64;
    const int col0 = (tile & 3) * 64;
    const int tid = threadIdx.x;
    const int tx = tid & 15, ty = tid >> 4;
    const int lr = tid >> 2;
    const int kq = (tid & 3) * 4;
    const float* Qb = Q + (size_t)b * N_ * KQ_;
    const float* Kbb = Kb + (size_t)b * N_ * KQ_;
    float acc[4][4] = {};
    for (int kt = 0; kt < KQ_; kt += 16) {
        float4 av = *(const float4*)&Qb[(size_t)(row0 + lr) * KQ_ + kt + kq];
        float4 bv = *(const float4*)&Kbb[(size_t)(col0 + lr) * KQ_ + kt + kq];
        __syncthreads();
        As[kq + 0][lr] = av.x; As[kq + 1][lr] = av.y; As[kq + 2][lr] = av.z; As[kq + 3][lr] = av.w;
        Bs[kq + 0][lr] = bv.x; Bs[kq + 1][lr] = bv.y; Bs[kq + 2][lr] = bv.z; Bs[kq + 3][lr] = bv.w;
        __syncthreads();
#pragma unroll
        for (int k = 0; k < 16; ++k) {
            float4 a = *(const float4*)&As[k][ty * 4];
            float4 c = *(const float4*)&Bs[k][tx * 4];
            acc[0][0] += a.x * c.x; acc[0][1] += a.x * c.y; acc[0][2] += a.x * c.z; acc[0][3] += a.x * c.w;
            acc[1][0] += a.y * c.x; acc[1][1] += a.y * c.y; acc[1][2] += a.y * c.z; acc[1][3] += a.y * c.w;
            acc[2][0] += a.z * c.x; acc[2][1] += a.z * c.y; acc[2][2] += a.z * c.z; acc[2][3] += a.z * c.w;
            acc[3][0] += a.w * c.x; acc[3][1] += a.w * c.y; acc[3][2] += a.w * c.z; acc[3][3] += a.w * c.w;
        }
    }
#pragma unroll
    for (int i = 0; i < 4; ++i) {
        float4 r = make_float4(acc[i][0] * SCALE_, acc[i][1] * SCALE_,
                               acc[i][2] * SCALE_, acc[i][3] * SCALE_);
        *(float4*)&sc[((size_t)b * N_ + row0 + ty * 4 + i) * N_ + col0 + tx * 4] = r;
    }
}

__global__ void softmax_kernel(float* __restrict__ sc)
{
    const int n = blockIdx.x, b = blockIdx.y;
    const int tid = threadIdx.x;
    __shared__ float red[256];
    float* row = sc + ((size_t)b * N_ + n) * N_;
    float v = row[tid];
    red[tid] = v;
    __syncthreads();
    for (int s = 128; s > 0; s >>= 1) {
        if (tid < s) red[tid] = fmaxf(red[tid], red[tid + s]);
        __syncthreads();
    }
    float m = red[0];
    __syncthreads();
    float e = expf(v - m);
    red[tid] = e;
    __syncthreads();
    for (int s = 128; s > 0; s >>= 1) {
        if (tid < s) red[tid] += red[tid + s];
        __syncthreads();
    }
    row[tid] = e / red[0];
}

// ctx[b][n][s] = sum_m W[b][n][m] * prev[b][m][s]
__global__ void ctx_kernel(const float* __restrict__ W, const float* __restrict__ prev,
                           float* __restrict__ ctx)
{
    __shared__ float As[16][64];
    __shared__ float Bs[16][64];
    const int b = blockIdx.y;
    const int tile = blockIdx.x;
    const int row0 = (tile >> 2) * 64;
    const int col0 = (tile & 3) * 64;
    const int tid = threadIdx.x;
    const int tx = tid & 15, ty = tid >> 4;
    const int lr = tid >> 2;
    const int kq = (tid & 3) * 4;
    const int br = tid >> 4;
    const int bc = (tid & 15) * 4;
    const float* Wb = W + (size_t)b * N_ * N_;
    const float* pb = prev + (size_t)b * N_ * S_;
    float acc[4][4] = {};
    for (int kt = 0; kt < N_; kt += 16) {
        float4 av = *(const float4*)&Wb[(size_t)(row0 + lr) * N_ + kt + kq];
        float4 bv = *(const float4*)&pb[(size_t)(kt + br) * S_ + col0 + bc];
        __syncthreads();
        As[kq + 0][lr] = av.x; As[kq + 1][lr] = av.y; As[kq + 2][lr] = av.z; As[kq + 3][lr] = av.w;
        *(float4*)&Bs[br][bc] = bv;
        __syncthreads();
#pragma unroll
        for (int k = 0; k < 16; ++k) {
            float4 a = *(const float4*)&As[k][ty * 4];
            float4 c = *(const float4*)&Bs[k][tx * 4];
            acc[0][0] += a.x * c.x; acc[0][1] += a.x * c.y; acc[0][2] += a.x * c.z; acc[0][3] += a.x * c.w;
            acc[1][0] += a.y * c.x; acc[1][1] += a.y * c.y; acc[1][2] += a.y * c.z; acc[1][3] += a.y * c.w;
            acc[2][0] += a.z * c.x; acc[2][1] += a.z * c.y; acc[2][2] += a.z * c.z; acc[2][3] += a.z * c.w;
            acc[3][0] += a.w * c.x; acc[3][1] += a.w * c.y; acc[3][2] += a.w * c.z; acc[3][3] += a.w * c.w;
        }
    }
#pragma unroll
    for (int i = 0; i < 4; ++i) {
        float4 r = make_float4(acc[i][0], acc[i][1], acc[i][2], acc[i][3]);
        *(float4*)&ctx[((size_t)b * N_ + row0 + ty * 4 + i) * S_ + col0 + tx * 4] = r;
    }
}

// ---------------------------------------------------------------------------
// cell: reduce 2 gate partials + biases, apply LSTM cell -> c, h
// ---------------------------------------------------------------------------
__global__ __launch_bounds__(256)
void cell_kernel(const float* __restrict__ P, const float* __restrict__ bih,
                 const float* __restrict__ bhh,
                 float* __restrict__ c, float* __restrict__ h)
{
    const int tid = blockIdx.x * 256 + threadIdx.x;
    const int bn = tid >> 8;
    const int hx = tid & 255;
    const int n = bn & 255;
    const size_t PG = (size_t)8 * N_ * G_; // one split's stride
    const size_t gb = (size_t)bn * G_;
    float g4[4];
#pragma unroll
    for (int gi = 0; gi < 4; ++gi) {
        int off = gi * 256 + hx;
        g4[gi] = P[gb + off] + P[PG + gb + off]
               + bih[n * G_ + off] + bhh[n * G_ + off];
    }
    float cv = c[tid];
    float cn = sigmoid_(g4[1]) * cv + sigmoid_(g4[0]) * tanhf(g4[2]);
    float hn = sigmoid_(g4[3]) * tanhf(cn);
    c[tid] = cn;
    h[tid] = hn;
}

// ---------------------------------------------------------------------------
// proj: out[b][t][o] = prev[b][224:,:].flat @ w_proj[o] + b_proj[o]
// ---------------------------------------------------------------------------
__global__ void proj_kernel(const float* __restrict__ prev, const float* __restrict__ wp,
                            const float* __restrict__ bp, float* __restrict__ out, int t)
{
    const int o = blockIdx.x;
    const int tid = threadIdx.x;
    float acc[8] = {};
    const float* wr = wp + (size_t)o * (32 * S_);
    for (int j = tid; j < 32 * S_; j += 256) {
        float w = wr[j];
#pragma unroll
        for (int b = 0; b < 8; ++b)
            acc[b] += w * prev[(size_t)b * N_ * S_ + 224 * S_ + j];
    }
    __shared__ float red[256];
#pragma unroll
    for (int b = 0; b < 8; ++b) {
        red[tid] = acc[b];
        __syncthreads();
        for (int s = 128; s > 0; s >>= 1) {
            if (tid < s) red[tid] += red[tid + s];
            __syncthreads();
        }
        if (tid == 0) out[((size_t)b * T_ + t) * OUTPUT_ + o] = red[0] + bp[o];
        __syncthreads();
    }
}

// ---------------------------------------------------------------------------
extern "C" void kernel_launch(void* const* d_in, const int* in_sizes, int n_in,
                              void* d_out, int out_size, void* d_ws, size_t ws_size,
                              hipStream_t stream)
{
    (void)in_sizes; (void)n_in; (void)out_size; (void)ws_size;
    const float* x    = (const float*)d_in[0];
    const float* w_ri = (const float*)d_in[1];
    const float* b_ri = (const float*)d_in[2];
    const float* w_ro = (const float*)d_in[3];
    const float* b_ro = (const float*)d_in[4];
    const float* w_ih = (const float*)d_in[5];
    const float* b_ih = (const float*)d_in[6];
    const float* w_hh = (const float*)d_in[7];
    const float* b_hh = (const float*)d_in[8];
    const float* w_q  = (const float*)d_in[9];
    const float* b_q  = (const float*)d_in[10];
    const float* w_k  = (const float*)d_in[11];
    const float* b_k  = (const float*)d_in[12];
    const float* w_s  = (const float*)d_in[13];
    const float* b_s  = (const float*)d_in[14];
    const float* w_p  = (const float*)d_in[15];
    const float* b_p  = (const float*)d_in[16];
    float* out = (float*)d_out;

    float* ws = (float*)d_ws;
    const size_t SZ = (size_t)B_ * N_ * H_; // 524288 floats = 2 MB
    float* hbuf = ws;
    float* cbuf = hbuf + SZ;
    float* prev = cbuf + SZ;
    float* Q    = prev + SZ;
    float* Kb   = Q + SZ;
    float* sc   = Kb + SZ;
    float* ctxb = sc + SZ;
    float* lin  = ctxb + SZ;
    float* Pbuf = lin + SZ;       // 8*SZ floats (16 MB), time-shared:
    float* Pq   = Pbuf;           //   [4][B][N][256]
    float* Pk   = Pbuf + 4 * SZ;  //   [4][B][N][256]
    float* Prec = Pbuf;           //   [4][B][N][256] (n>=32 rows used)
    float* Pg   = Pbuf;           //   [2][B][N][1024]
    float* Ps   = Pbuf;           //   [4][B][N][256]

    hipMemsetAsync(d_ws, 0, 3 * SZ * sizeof(float), stream); // h, c, prev = 0

    for (int t = 0; t < T_; ++t) {
        // Q,K = h @ w_q/w_k (fused via grid.z)
        pnmm64_kernel<<<dim3(4, 256, 2), 64, 0, stream>>>(hbuf, w_q, Pq, w_k, Pk, 0);
        reduceQK_kernel<<<dim3(512, 2), 256, 0, stream>>>(Pq, Pk, b_q, b_k, Q, Kb);
        scores_kernel<<<dim3(16, B_), 256, 0, stream>>>(Q, Kb, sc);
        softmax_kernel<<<dim3(N_, B_), 256, 0, stream>>>(sc);
        ctx_kernel<<<dim3(16, B_), 256, 0, stream>>>(sc, prev, ctxb);
        // lstm_in
        rec_in_kernel<<<dim3(NIN_), 256, 0, stream>>>(x, t, w_ri, b_ri, lin);
        pnmm64_kernel<<<dim3(4, 224, 1), 64, 0, stream>>>(ctxb, w_ro, Prec, w_ro, Prec, NIN_);
        reduce4_kernel<<<dim3(448), 256, 0, stream>>>(Prec, b_ro, lin, NIN_, 224, 1);
        // gates + cell
        gates_mm_kernel<<<dim3(2, 256), 256, 0, stream>>>(lin, hbuf, w_ih, w_hh, Pg);
        cell_kernel<<<dim3(2048), 256, 0, stream>>>(Pg, b_ih, b_hh, cbuf, hbuf);
        // prev = h_new @ w_sender
        pnmm64_kernel<<<dim3(4, 256, 1), 64, 0, stream>>>(hbuf, w_s, Ps, w_s, Ps, 0);
        reduce4_kernel<<<dim3(512), 256, 0, stream>>>(Ps, b_s, prev, 0, 256, 0);
        proj_kernel<<<dim3(OUTPUT_), 256, 0, stream>>>(prev, w_p, b_p, out, t);
    }
}